// Round 5
// baseline (1155.106 us; speedup 1.0000x reference)
//
#include <hip/hip_runtime.h>
#include <stdint.h>

typedef unsigned long long ull;
typedef float f32x2 __attribute__((ext_vector_type(2)));

#define NBATCH 8
#define NPTS   4096
#define NS     1024
#define NK     16
#define NF     64
#define NO     128

#define FT  256  // fps threads (4 waves, 1 per SIMD)
#define PPT 16   // points per thread

static __device__ __forceinline__ ull umax64(ull a, ull b) { return a > b ? a : b; }

// DPP max-reduce of a 64-bit key across the 64-lane wave; result in lane 63.
static __device__ __forceinline__ ull dpp_reduce_max_u64(ull v) {
#define DPP_STEP(ctrl)                                                        \
  {                                                                           \
    const unsigned lo = (unsigned)v;                                          \
    const unsigned hi = (unsigned)(v >> 32);                                  \
    const unsigned lo2 =                                                      \
        (unsigned)__builtin_amdgcn_update_dpp(0, (int)lo, ctrl, 0xf, 0xf, true); \
    const unsigned hi2 =                                                      \
        (unsigned)__builtin_amdgcn_update_dpp(0, (int)hi, ctrl, 0xf, 0xf, true); \
    const ull o = ((ull)hi2 << 32) | lo2;                                     \
    v = v > o ? v : o;                                                        \
  }
  DPP_STEP(0x111)  // row_shr:1
  DPP_STEP(0x112)  // row_shr:2
  DPP_STEP(0x114)  // row_shr:4
  DPP_STEP(0x118)  // row_shr:8  -> lane {15,31,47,63} = row max
  DPP_STEP(0x142)  // row_bcast15 -> lane 31 (rows 0-1), lane 63 (rows 2-3)
  DPP_STEP(0x143)  // row_bcast31 -> lane 63 = wave max
#undef DPP_STEP
  return v;
}

// ---------------------------------------------------------------------------
// FPS: one block per batch, 256 threads, 16 points/thread. Packed-f32 distance
// math (v_pk_*, IEEE f32, contract off => bit-exact vs numpy ((dx^2+dy^2)+dz^2)).
// Winner coords travel WITH the key through the cross-wave merge (32B LDS
// entries), so the post-merge serial plds coords read is eliminated.
// No global stores in the loop; winners dumped once at the end.
// ---------------------------------------------------------------------------
__global__ __launch_bounds__(FT) void fps_kernel(const float* __restrict__ pos,
                                                 int* __restrict__ fps_idx,
                                                 float* __restrict__ out_pos) {
#pragma clang fp contract(off)
  const int b = blockIdx.x;
  const int t = threadIdx.x;
  __shared__ float plds[NPTS * 3];
  __shared__ __align__(16) float went[2][4][8];  // [key_lo,key_hi,x,y,z,pad×3]
  __shared__ int widx_lds[NS];

  const float* p = pos + (size_t)b * NPTS * 3;
  {
    const float4* src = (const float4*)p;
    float4* dst = (float4*)plds;
    for (int i = t; i < NPTS * 3 / 4; i += FT) dst[i] = src[i];
  }
  if (t == 0) widx_lds[0] = 0;
  __syncthreads();

  f32x2 px2[PPT / 2], py2[PPT / 2], pz2[PPT / 2], md2[PPT / 2];
  unsigned lowk[PPT];
#pragma unroll
  for (int jp = 0; jp < PPT / 2; ++jp) {
    const int i0 = t + FT * (2 * jp);
    const int i1 = i0 + FT;
    px2[jp] = (f32x2){plds[3 * i0 + 0], plds[3 * i1 + 0]};
    py2[jp] = (f32x2){plds[3 * i0 + 1], plds[3 * i1 + 1]};
    pz2[jp] = (f32x2){plds[3 * i0 + 2], plds[3 * i1 + 2]};
    md2[jp] = (f32x2){1e10f, 1e10f};
    lowk[2 * jp] = 4095 - i0;
    lowk[2 * jp + 1] = 4095 - i1;
  }

  float lx = plds[0], ly = plds[1], lz = plds[2];

  for (int s = 1; s < NS; ++s) {
    const f32x2 lxv = (f32x2){lx, lx};
    const f32x2 lyv = (f32x2){ly, ly};
    const f32x2 lzv = (f32x2){lz, lz};
    ull kp[PPT / 2];
#pragma unroll
    for (int jp = 0; jp < PPT / 2; ++jp) {
      const f32x2 dx = px2[jp] - lxv;  // v_pk_add(neg) — IEEE f32
      const f32x2 dy = py2[jp] - lyv;
      const f32x2 dz = pz2[jp] - lzv;
      const f32x2 xx = dx * dx;        // v_pk_mul
      const f32x2 yy = dy * dy;
      const f32x2 zz = dz * dz;
      const f32x2 sxy = xx + yy;
      const f32x2 d = sxy + zz;        // ((dx^2+dy^2)+dz^2), numpy order
      const float m0 = fminf(md2[jp].x, d.x);
      const float m1 = fminf(md2[jp].y, d.y);
      md2[jp].x = m0;
      md2[jp].y = m1;
      const ull k0 = ((ull)__float_as_uint(m0) << 32) | lowk[2 * jp];
      const ull k1 = ((ull)__float_as_uint(m1) << 32) | lowk[2 * jp + 1];
      kp[jp] = umax64(k0, k1);
    }
    // balanced tree over the 8 pair-keys (independent chains)
    const ull t01 = umax64(kp[0], kp[1]);
    const ull t23 = umax64(kp[2], kp[3]);
    const ull t45 = umax64(kp[4], kp[5]);
    const ull t67 = umax64(kp[6], kp[7]);
    ull best = umax64(umax64(t01, t23), umax64(t45, t67));

    best = dpp_reduce_max_u64(best);
    const int sl = s & 1;
    if ((t & 63) == 63) {
      // this wave's candidate: fetch ITS coords pre-barrier, publish with key
      const int wi = 4095 - (int)(best & 0xFFFFFFFFu);
      const float cx = plds[3 * wi + 0];
      const float cy = plds[3 * wi + 1];
      const float cz = plds[3 * wi + 2];
      float* e = went[sl][t >> 6];
      *(float4*)e = (float4){__uint_as_float((unsigned)best),
                            __uint_as_float((unsigned)(best >> 32)), cx, cy};
      e[4] = cz;
    }
    __syncthreads();
    // merge 4 (key,x,y,z) entries — all-thread broadcast reads, cndmask selects
    const float4 e0 = *(const float4*)went[sl][0];
    const float z0f = went[sl][0][4];
    const float4 e1 = *(const float4*)went[sl][1];
    const float z1f = went[sl][1][4];
    const float4 e2 = *(const float4*)went[sl][2];
    const float z2f = went[sl][2][4];
    const float4 e3 = *(const float4*)went[sl][3];
    const float z3f = went[sl][3][4];
    const ull k0 = ((ull)__float_as_uint(e0.y) << 32) | __float_as_uint(e0.x);
    const ull k1 = ((ull)__float_as_uint(e1.y) << 32) | __float_as_uint(e1.x);
    const ull k2 = ((ull)__float_as_uint(e2.y) << 32) | __float_as_uint(e2.x);
    const ull k3 = ((ull)__float_as_uint(e3.y) << 32) | __float_as_uint(e3.x);
    const bool c01 = k1 > k0;
    const ull k01 = c01 ? k1 : k0;
    const float x01 = c01 ? e1.z : e0.z, y01 = c01 ? e1.w : e0.w,
                z01 = c01 ? z1f : z0f;
    const bool c23 = k3 > k2;
    const ull k23 = c23 ? k3 : k2;
    const float x23 = c23 ? e3.z : e2.z, y23 = c23 ? e3.w : e2.w,
                z23 = c23 ? z3f : z2f;
    const bool cf = k23 > k01;
    const ull kk = cf ? k23 : k01;
    lx = cf ? x23 : x01;
    ly = cf ? y23 : y01;
    lz = cf ? z23 : z01;
    if (t == 0) widx_lds[s] = 4095 - (int)(kk & 0xFFFFFFFFu);
    // went double-buffered: next write to this slot (s+2) is after barrier s+1.
  }

  __syncthreads();
  for (int i = t; i < NS; i += FT) {
    const int wi = widx_lds[i];
    fps_idx[b * NS + i] = wi;
    out_pos[((size_t)b * NS + i) * 3 + 0] = plds[3 * wi + 0];
    out_pos[((size_t)b * NS + i) * 3 + 1] = plds[3 * wi + 1];
    out_pos[((size_t)b * NS + i) * 3 + 2] = plds[3 * wi + 2];
  }
}

// ---------------------------------------------------------------------------
// KNN: block = 32 samples x 8 chunks (256 threads), batch pos in LDS.
// ---------------------------------------------------------------------------
__global__ __launch_bounds__(256) void knn_kernel(const float* __restrict__ pos,
                                                  const int* __restrict__ fps_idx,
                                                  int* __restrict__ knn_idx) {
  __shared__ ull sbuf[NPTS * 3 / 2];  // 48KB, floats during scan, keys after
  float* plds = (float*)sbuf;
  const int b = blockIdx.y;
  const int t = threadIdx.x;

  const float* p = pos + (size_t)b * NPTS * 3;
  for (int i = t; i < NPTS * 3; i += 256) plds[i] = p[i];
  __syncthreads();

  const int samp = blockIdx.x * 32 + (t >> 3);
  const int chunk = t & 7;
  const int sidx = fps_idx[b * NS + samp];
  const float sx = plds[sidx * 3 + 0];
  const float sy = plds[sidx * 3 + 1];
  const float sz = plds[sidx * 3 + 2];

  ull keys[16];
#pragma unroll
  for (int k = 0; k < 16; ++k) keys[k] = 0xFFFFFFFF00000000ull | (unsigned)k;
  ull worst = 0xFFFFFFFF0000000Full;

  for (int j = 0; j < 512; ++j) {
    const int i = j * 8 + chunk;
    const float dx = plds[i * 3 + 0] - sx;
    const float dy = plds[i * 3 + 1] - sy;
    const float dz = plds[i * 3 + 2] - sz;
    const float d = dx * dx + dy * dy + dz * dz;
    const ull key = ((ull)__float_as_uint(d) << 32) | (unsigned)i;
    if (key < worst) {
#pragma unroll
      for (int k = 0; k < 16; ++k) keys[k] = (keys[k] == worst) ? key : keys[k];
      ull w = keys[0];
#pragma unroll
      for (int k = 1; k < 16; ++k) w = umax64(w, keys[k]);
      worst = w;
    }
  }
  __syncthreads();
#pragma unroll
  for (int k = 0; k < 16; ++k) sbuf[t * 16 + k] = keys[k];
  __syncthreads();

  if (t < 32) {
    ull best[16];
#pragma unroll
    for (int k = 0; k < 16; ++k) best[k] = 0xFFFFFFFF00000000ull | (unsigned)(64 + k);
    ull w = 0xFFFFFFFF00000000ull | (unsigned)(64 + 15);
    for (int c = 0; c < 8; ++c) {
#pragma unroll
      for (int k = 0; k < 16; ++k) {
        const ull key = sbuf[(t * 8 + c) * 16 + k];
        if (key < w) {
#pragma unroll
          for (int q = 0; q < 16; ++q) best[q] = (best[q] == w) ? key : best[q];
          ull nw = best[0];
#pragma unroll
          for (int q = 1; q < 16; ++q) nw = umax64(nw, best[q]);
          w = nw;
        }
      }
    }
    const int sampg = blockIdx.x * 32 + t;
#pragma unroll
    for (int k = 0; k < 16; ++k)
      knn_idx[((size_t)b * NS + sampg) * NK + k] = (int)(best[k] & 0xFFFFFFFFu);
  }
}

// ---------------------------------------------------------------------------
// Stats: per-channel sum / sumsq of h = x W^T + b without materializing h.
// ---------------------------------------------------------------------------
__global__ __launch_bounds__(128) void stats_kernel(const float* __restrict__ x,
                                                    const float* __restrict__ W,
                                                    const float* __restrict__ bias,
                                                    float* __restrict__ partial) {
  const int blk = blockIdx.x;
  const int c = threadIdx.x;
  __shared__ float xl[128 * 64];

  const float4* Wv = (const float4*)(W + c * NF);
  float4 w[16];
#pragma unroll
  for (int q = 0; q < 16; ++q) w[q] = Wv[q];
  const float bb = bias[c];

  const float4* src = (const float4*)(x + (size_t)blk * 128 * NF);
  float4* dst = (float4*)xl;
  for (int i = c; i < 128 * NF / 4; i += 128) dst[i] = src[i];
  __syncthreads();

  float s = 0.f, s2 = 0.f;
  for (int r = 0; r < 128; ++r) {
    const float4* xr = (const float4*)(xl + r * NF);
    float h = bb;
#pragma unroll
    for (int q = 0; q < 16; ++q) {
      const float4 xv = xr[q];
      h = fmaf(xv.x, w[q].x, h);
      h = fmaf(xv.y, w[q].y, h);
      h = fmaf(xv.z, w[q].z, h);
      h = fmaf(xv.w, w[q].w, h);
    }
    s += h;
    s2 = fmaf(h, h, s2);
  }
  partial[blk * 256 + c] = s;
  partial[blk * 256 + 128 + c] = s2;
}

__global__ __launch_bounds__(256) void stats_reduce_kernel(
    const float* __restrict__ partial, const float* __restrict__ gamma,
    const float* __restrict__ beta, float* __restrict__ ab) {
  const int t = threadIdx.x;
  const int c = t & 127;
  const int h = t >> 7;
  __shared__ double sred[256], s2red[256];
  double s = 0.0, s2 = 0.0;
#pragma unroll 4
  for (int blk = h * 128; blk < h * 128 + 128; ++blk) {
    s += (double)partial[blk * 256 + c];
    s2 += (double)partial[blk * 256 + 128 + c];
  }
  sred[t] = s;
  s2red[t] = s2;
  __syncthreads();
  if (t < 128) {
    s = sred[t] + sred[t + 128];
    s2 = s2red[t] + s2red[t + 128];
    const double n = 32768.0;
    const double mean = s / n;
    const double var = s2 / n - mean * mean;
    const float inv = (float)(1.0 / sqrt(var + 1e-5));
    const float scale = gamma[t] * inv;
    const float shift = beta[t] - (float)mean * scale;
    ab[t] = scale;
    ab[128 + t] = shift;
  }
}

// ---------------------------------------------------------------------------
// Gather-max: block = 8 samples of one batch, 256 threads. Thread owns TWO
// channels (c2, c2+64) — halves the CU-shared LDS ds_read_b128 issue count.
// Group g = t>>6 handles samples {2g, 2g+1}.
// ---------------------------------------------------------------------------
__global__ __launch_bounds__(256) void gather_kernel(const float* __restrict__ x,
                                                     const float* __restrict__ W,
                                                     const float* __restrict__ bias,
                                                     const float* __restrict__ ab,
                                                     const int* __restrict__ knn_idx,
                                                     float* __restrict__ out) {
  const int b = blockIdx.y;
  const int s0 = blockIdx.x * 8;
  const int t = threadIdx.x;
  const int c2 = t & 63;
  const int g = t >> 6;

  float4 w0[16], w1[16];
  {
    const float4* Wv0 = (const float4*)(W + c2 * NF);
    const float4* Wv1 = (const float4*)(W + (c2 + 64) * NF);
#pragma unroll
    for (int q = 0; q < 16; ++q) {
      w0[q] = Wv0[q];
      w1[q] = Wv1[q];
    }
  }
  const float bb0 = bias[c2], bb1 = bias[c2 + 64];
  const float scale0 = ab[c2], scale1 = ab[c2 + 64];
  const float shift0 = ab[128 + c2], shift1 = ab[128 + c2 + 64];

  __shared__ float xl[128 * NF];  // 32KB: row r = (sample s0+(r>>4), neighbor r&15)
  {
    const int r = t & 127;
    const int q0 = (t >> 7) * 8;
    const int idx = knn_idx[((size_t)b * NS + s0 + (r >> 4)) * NK + (r & 15)];
    const float4* srow =
        (const float4*)(x + (size_t)b * NPTS * NF + (size_t)idx * NF) + q0;
    float4* drow = (float4*)(xl + r * NF) + q0;
#pragma unroll
    for (int q = 0; q < 8; ++q) drow[q] = srow[q];
  }
  __syncthreads();

#pragma unroll
  for (int sg = 0; sg < 2; ++sg) {
    const int ss = 2 * g + sg;
    float m0 = 0.0f, m1 = 0.0f;  // relu >= 0
#pragma unroll
    for (int k = 0; k < NK; ++k) {
      const float4* xr = (const float4*)(xl + (ss * 16 + k) * NF);
      float h0 = bb0, h1 = bb1;
#pragma unroll
      for (int q = 0; q < 16; ++q) {
        const float4 xv = xr[q];
        h0 = fmaf(xv.x, w0[q].x, h0);
        h0 = fmaf(xv.y, w0[q].y, h0);
        h0 = fmaf(xv.z, w0[q].z, h0);
        h0 = fmaf(xv.w, w0[q].w, h0);
        h1 = fmaf(xv.x, w1[q].x, h1);
        h1 = fmaf(xv.y, w1[q].y, h1);
        h1 = fmaf(xv.z, w1[q].z, h1);
        h1 = fmaf(xv.w, w1[q].w, h1);
      }
      h0 = fmaf(h0, scale0, shift0);
      h1 = fmaf(h1, scale1, shift1);
      h0 = h0 > 0.f ? h0 : 0.f;
      h1 = h1 > 0.f ? h1 : 0.f;
      m0 = m0 > h0 ? m0 : h0;
      m1 = m1 > h1 ? m1 : h1;
    }
    float* o = out + ((size_t)b * NS + s0 + ss) * NO;
    o[c2] = m0;
    o[c2 + 64] = m1;
  }
}

// ---------------------------------------------------------------------------
extern "C" void kernel_launch(void* const* d_in, const int* in_sizes, int n_in,
                              void* d_out, int out_size, void* d_ws, size_t ws_size,
                              hipStream_t stream) {
  const float* x     = (const float*)d_in[0];  // [8,4096,64]
  const float* pos   = (const float*)d_in[1];  // [8,4096,3]
  const float* W     = (const float*)d_in[2];  // [128,64]
  const float* bias  = (const float*)d_in[3];  // [128]
  const float* gamma = (const float*)d_in[4];  // [128]
  const float* beta  = (const float*)d_in[5];  // [128]

  float* out_knn = (float*)d_out;                       // [8,1024,128]
  float* out_pos = out_knn + (size_t)NBATCH * NS * NO;  // [8,1024,3]

  char* ws = (char*)d_ws;
  int* fps_idx   = (int*)(ws);                 // 8*1024 ints      (32KB)
  int* knn_idx   = (int*)(ws + (32 << 10));    // 8*1024*16 ints   (512KB)
  float* partial = (float*)(ws + (544 << 10)); // 256*256 floats   (256KB)
  float* ab      = (float*)(ws + (800 << 10)); // 256 floats

  fps_kernel<<<NBATCH, FT, 0, stream>>>(pos, fps_idx, out_pos);
  stats_kernel<<<256, 128, 0, stream>>>(x, W, bias, partial);
  stats_reduce_kernel<<<1, 256, 0, stream>>>(partial, gamma, beta, ab);
  knn_kernel<<<dim3(32, NBATCH), 256, 0, stream>>>(pos, fps_idx, knn_idx);
  gather_kernel<<<dim3(NS / 8, NBATCH), 256, 0, stream>>>(x, W, bias, ab, knn_idx,
                                                          out_knn);
}

// Round 6
// 1138.319 us; speedup vs baseline: 1.0147x; 1.0147x over previous
//
#include <hip/hip_runtime.h>
#include <stdint.h>

typedef unsigned long long ull;
typedef float f32x2 __attribute__((ext_vector_type(2)));

#define NBATCH 8
#define NPTS   4096
#define NS     1024
#define NK     16
#define NF     64
#define NO     128

#define FT  256  // fps threads (4 waves, 1 per SIMD)
#define PPT 16   // points per thread

static __device__ __forceinline__ ull umax64(ull a, ull b) { return a > b ? a : b; }

// DPP max-reduce of an f32 across the 64-lane wave; result in lane 63.
// bound_ctrl=true fills invalid lanes with 0.0f — neutral (all values >= 0).
static __device__ __forceinline__ float dpp_max_f32(float v) {
#define DPP_STEP(ctrl)                                                      \
  {                                                                         \
    const float o = __int_as_float(                                         \
        __builtin_amdgcn_update_dpp(0, __float_as_int(v), ctrl, 0xf, 0xf, true)); \
    v = fmaxf(v, o);                                                        \
  }
  DPP_STEP(0x111)  // row_shr:1
  DPP_STEP(0x112)  // row_shr:2
  DPP_STEP(0x114)  // row_shr:4
  DPP_STEP(0x118)  // row_shr:8
  DPP_STEP(0x142)  // row_bcast15
  DPP_STEP(0x143)  // row_bcast31 -> lane 63 = wave max
#undef DPP_STEP
  return v;
}

// ---------------------------------------------------------------------------
// Fused kernel 1.
// Blocks 0..7: FPS, one block per batch, 256 threads, 16 pts/thread.
//   Pure-f32 tournament: packed (v_pk_) sub/mul/add in numpy's ((dx²+dy²)+dz²)
//   order (contract off => bit-exact), v_pk_min/v_pk_max tracking. Winner
//   index recovered post-merge by bit-equality scan of register md values
//   (max chain is pure selection => M is bitwise one of the md values; exact
//   ties are measure-zero in random data). Winner thread publishes
//   idx+coords; second barrier broadcasts.
// Blocks 8..263: per-channel partial sums of h = x W^T + b (stats).
// ---------------------------------------------------------------------------
__global__ __launch_bounds__(256) void fps_stats_kernel(
    const float* __restrict__ pos, const float* __restrict__ x,
    const float* __restrict__ W, const float* __restrict__ bias,
    int* __restrict__ fps_idx, float* __restrict__ out_pos,
    float* __restrict__ partial) {
#pragma clang fp contract(off)
  const int t = threadIdx.x;
  __shared__ float plds[NPTS * 3];  // fps: points | stats: x tile (32KB used)
  __shared__ float wmax[4];
  __shared__ float went[4];  // x,y,z,bitcast(idx)
  __shared__ int widx_lds[NS];

  if (blockIdx.x >= 8) {
    // ------------------------- stats branch --------------------------------
    const int blk = blockIdx.x - 8;
    const int c = t & 127;
    const int h = t >> 7;
    float* xl = plds;

    const float4* Wv = (const float4*)(W + c * NF);
    float4 w[16];
#pragma unroll
    for (int q = 0; q < 16; ++q) w[q] = Wv[q];
    const float bb = bias[c];

    const float4* src = (const float4*)(x + (size_t)blk * 128 * NF);
    float4* dst = (float4*)xl;
    for (int i = t; i < 128 * NF / 4; i += 256) dst[i] = src[i];
    __syncthreads();

    float s = 0.f, s2 = 0.f;
    for (int r = h * 64; r < h * 64 + 64; ++r) {
      const float4* xr = (const float4*)(xl + r * NF);
      float hh = bb;
#pragma unroll
      for (int q = 0; q < 16; ++q) {
        const float4 xv = xr[q];
        hh = fmaf(xv.x, w[q].x, hh);
        hh = fmaf(xv.y, w[q].y, hh);
        hh = fmaf(xv.z, w[q].z, hh);
        hh = fmaf(xv.w, w[q].w, hh);
      }
      s += hh;
      s2 = fmaf(hh, hh, s2);
    }
    partial[(blk * 2 + h) * 256 + c] = s;
    partial[(blk * 2 + h) * 256 + 128 + c] = s2;
    return;
  }

  // --------------------------- fps branch ----------------------------------
  const int b = blockIdx.x;
  const float* p = pos + (size_t)b * NPTS * 3;
  {
    const float4* src = (const float4*)p;
    float4* dst = (float4*)plds;
    for (int i = t; i < NPTS * 3 / 4; i += FT) dst[i] = src[i];
  }
  if (t == 0) widx_lds[0] = 0;
  __syncthreads();

  f32x2 px2[PPT / 2], py2[PPT / 2], pz2[PPT / 2], md2[PPT / 2];
#pragma unroll
  for (int jp = 0; jp < PPT / 2; ++jp) {
    const int i0 = t + FT * (2 * jp);
    const int i1 = i0 + FT;
    px2[jp] = (f32x2){plds[3 * i0 + 0], plds[3 * i1 + 0]};
    py2[jp] = (f32x2){plds[3 * i0 + 1], plds[3 * i1 + 1]};
    pz2[jp] = (f32x2){plds[3 * i0 + 2], plds[3 * i1 + 2]};
    md2[jp] = (f32x2){1e10f, 1e10f};
  }

  float lx = plds[0], ly = plds[1], lz = plds[2];

  for (int s = 1; s < NS; ++s) {
    const f32x2 lxv = (f32x2){lx, lx};
    const f32x2 lyv = (f32x2){ly, ly};
    const f32x2 lzv = (f32x2){lz, lz};
    f32x2 acc = (f32x2){0.f, 0.f};
#pragma unroll
    for (int jp = 0; jp < PPT / 2; ++jp) {
      const f32x2 dx = px2[jp] - lxv;  // v_pk_add(neg), IEEE f32
      const f32x2 dy = py2[jp] - lyv;
      const f32x2 dz = pz2[jp] - lzv;
      const f32x2 xx = dx * dx;        // v_pk_mul
      const f32x2 yy = dy * dy;
      const f32x2 zz = dz * dz;
      const f32x2 sxy = xx + yy;
      const f32x2 d = sxy + zz;        // ((dx²+dy²)+dz²), numpy order
      md2[jp] = __builtin_elementwise_min(md2[jp], d);   // v_pk_min_f32
      acc = __builtin_elementwise_max(acc, md2[jp]);     // v_pk_max_f32
    }
    float vmax = fmaxf(acc.x, acc.y);
    vmax = dpp_max_f32(vmax);
    if ((t & 63) == 63) wmax[t >> 6] = vmax;
    __syncthreads();
    const float4 wm = *(const float4*)wmax;
    const float M = fmaxf(fmaxf(wm.x, wm.y), fmaxf(wm.z, wm.w));
    // owner scan: descending so the smallest index wins within a thread
    int local = -1;
#pragma unroll
    for (int jp = PPT / 2 - 1; jp >= 0; --jp) {
      if (md2[jp].y == M) local = t + FT * (2 * jp) + FT;
      if (md2[jp].x == M) local = t + FT * (2 * jp);
    }
    if (local >= 0) {
      went[0] = plds[3 * local + 0];
      went[1] = plds[3 * local + 1];
      went[2] = plds[3 * local + 2];
      went[3] = __int_as_float(local);
    }
    __syncthreads();
    lx = went[0];
    ly = went[1];
    lz = went[2];
    if (t == 0) widx_lds[s] = __float_as_int(went[3]);
    // wmax/went single-buffered: each region's next write is separated from
    // this step's reads by one of the two barriers per step.
  }

  __syncthreads();
  for (int i = t; i < NS; i += FT) {
    const int wi = widx_lds[i];
    fps_idx[b * NS + i] = wi;
    out_pos[((size_t)b * NS + i) * 3 + 0] = plds[3 * wi + 0];
    out_pos[((size_t)b * NS + i) * 3 + 1] = plds[3 * wi + 1];
    out_pos[((size_t)b * NS + i) * 3 + 2] = plds[3 * wi + 2];
  }
}

// ---------------------------------------------------------------------------
// Stats reduce: 512 partial rows -> per-channel scale/shift.
// ---------------------------------------------------------------------------
__global__ __launch_bounds__(256) void stats_reduce_kernel(
    const float* __restrict__ partial, const float* __restrict__ gamma,
    const float* __restrict__ beta, float* __restrict__ ab) {
  const int t = threadIdx.x;
  const int c = t & 127;
  const int pp = t >> 7;
  __shared__ double sred[256], s2red[256];
  double s = 0.0, s2 = 0.0;
#pragma unroll 4
  for (int i = pp * 256; i < pp * 256 + 256; ++i) {
    s += (double)partial[i * 256 + c];
    s2 += (double)partial[i * 256 + 128 + c];
  }
  sred[t] = s;
  s2red[t] = s2;
  __syncthreads();
  if (t < 128) {
    s = sred[t] + sred[t + 128];
    s2 = s2red[t] + s2red[t + 128];
    const double n = 32768.0;
    const double mean = s / n;
    const double var = s2 / n - mean * mean;
    const float inv = (float)(1.0 / sqrt(var + 1e-5));
    const float scale = gamma[t] * inv;
    const float shift = beta[t] - (float)mean * scale;
    ab[t] = scale;
    ab[128 + t] = shift;
  }
}

// ---------------------------------------------------------------------------
// Fused kernel 2: block (x,b) computes KNN for its 32 samples (keys in LDS,
// indices to il2), then gathers/computes/maxes those same samples in 4 passes
// of 8 (xl reuses the keys region). No global knn_idx, no cross-block deps.
// ---------------------------------------------------------------------------
__global__ __launch_bounds__(256) void knn_gather_kernel(
    const float* __restrict__ pos, const int* __restrict__ fps_idx,
    const float* __restrict__ x, const float* __restrict__ W,
    const float* __restrict__ bias, const float* __restrict__ ab,
    float* __restrict__ out) {
  __shared__ ull sbuf[NPTS * 3 / 2];  // 48KB: pos floats -> keys -> x tile
  __shared__ int il2[32 * NK];        // 2KB: knn indices, block-local samples
  float* plds = (float*)sbuf;
  const int b = blockIdx.y;
  const int t = threadIdx.x;

  const float* p = pos + (size_t)b * NPTS * 3;
  for (int i = t; i < NPTS * 3; i += 256) plds[i] = p[i];
  __syncthreads();

  {
    const int samp = blockIdx.x * 32 + (t >> 3);
    const int chunk = t & 7;
    const int sidx = fps_idx[b * NS + samp];
    const float sx = plds[sidx * 3 + 0];
    const float sy = plds[sidx * 3 + 1];
    const float sz = plds[sidx * 3 + 2];

    ull keys[16];
#pragma unroll
    for (int k = 0; k < 16; ++k) keys[k] = 0xFFFFFFFF00000000ull | (unsigned)k;
    ull worst = 0xFFFFFFFF0000000Full;

    for (int j = 0; j < 512; ++j) {
      const int i = j * 8 + chunk;
      const float dx = plds[i * 3 + 0] - sx;
      const float dy = plds[i * 3 + 1] - sy;
      const float dz = plds[i * 3 + 2] - sz;
      const float d = dx * dx + dy * dy + dz * dz;
      const ull key = ((ull)__float_as_uint(d) << 32) | (unsigned)i;
      if (key < worst) {
#pragma unroll
        for (int k = 0; k < 16; ++k) keys[k] = (keys[k] == worst) ? key : keys[k];
        ull w = keys[0];
#pragma unroll
        for (int k = 1; k < 16; ++k) w = umax64(w, keys[k]);
        worst = w;
      }
    }
    __syncthreads();  // done reading plds as floats
#pragma unroll
    for (int k = 0; k < 16; ++k) sbuf[t * 16 + k] = keys[k];
    __syncthreads();

    if (t < 32) {
      ull best[16];
#pragma unroll
      for (int k = 0; k < 16; ++k)
        best[k] = 0xFFFFFFFF00000000ull | (unsigned)(64 + k);
      ull w = 0xFFFFFFFF00000000ull | (unsigned)(64 + 15);
      for (int c = 0; c < 8; ++c) {
#pragma unroll
        for (int k = 0; k < 16; ++k) {
          const ull key = sbuf[(t * 8 + c) * 16 + k];
          if (key < w) {
#pragma unroll
            for (int q = 0; q < 16; ++q) best[q] = (best[q] == w) ? key : best[q];
            ull nw = best[0];
#pragma unroll
            for (int q = 1; q < 16; ++q) nw = umax64(nw, best[q]);
            w = nw;
          }
        }
      }
#pragma unroll
      for (int k = 0; k < 16; ++k)
        il2[t * NK + k] = (int)(best[k] & 0xFFFFFFFFu);
    }
  }

  // ----------------------------- gather phase ------------------------------
  const int c2 = t & 63;
  const int g = t >> 6;
  float4 w0[16], w1[16];
  {
    const float4* Wv0 = (const float4*)(W + c2 * NF);
    const float4* Wv1 = (const float4*)(W + (c2 + 64) * NF);
#pragma unroll
    for (int q = 0; q < 16; ++q) {
      w0[q] = Wv0[q];
      w1[q] = Wv1[q];
    }
  }
  const float bb0 = bias[c2], bb1 = bias[c2 + 64];
  const float scale0 = ab[c2], scale1 = ab[c2 + 64];
  const float shift0 = ab[128 + c2], shift1 = ab[128 + c2 + 64];

  float* xl = (float*)sbuf;  // keys region dead after il2 is written
  const float* xb = x + (size_t)b * NPTS * NF;

  for (int pass = 0; pass < 4; ++pass) {
    __syncthreads();  // il2 ready (pass 0) / previous compute done (pass>0)
    {
      const int r = t & 127;
      const int q0 = (t >> 7) * 8;
      const int idx = il2[(pass * 8 + (r >> 4)) * NK + (r & 15)];
      const float4* srow = (const float4*)(xb + (size_t)idx * NF) + q0;
      float4* drow = (float4*)(xl + r * NF) + q0;
#pragma unroll
      for (int q = 0; q < 8; ++q) drow[q] = srow[q];
    }
    __syncthreads();

#pragma unroll
    for (int sg = 0; sg < 2; ++sg) {
      const int ss = 2 * g + sg;
      float m0 = 0.0f, m1 = 0.0f;  // relu >= 0
#pragma unroll
      for (int k = 0; k < NK; ++k) {
        const float4* xr = (const float4*)(xl + (ss * 16 + k) * NF);
        float h0 = bb0, h1 = bb1;
#pragma unroll
        for (int q = 0; q < 16; ++q) {
          const float4 xv = xr[q];
          h0 = fmaf(xv.x, w0[q].x, h0);
          h0 = fmaf(xv.y, w0[q].y, h0);
          h0 = fmaf(xv.z, w0[q].z, h0);
          h0 = fmaf(xv.w, w0[q].w, h0);
          h1 = fmaf(xv.x, w1[q].x, h1);
          h1 = fmaf(xv.y, w1[q].y, h1);
          h1 = fmaf(xv.z, w1[q].z, h1);
          h1 = fmaf(xv.w, w1[q].w, h1);
        }
        h0 = fmaf(h0, scale0, shift0);
        h1 = fmaf(h1, scale1, shift1);
        h0 = h0 > 0.f ? h0 : 0.f;
        h1 = h1 > 0.f ? h1 : 0.f;
        m0 = m0 > h0 ? m0 : h0;
        m1 = m1 > h1 ? m1 : h1;
      }
      float* o = out + ((size_t)b * NS + blockIdx.x * 32 + pass * 8 + ss) * NO;
      o[c2] = m0;
      o[c2 + 64] = m1;
    }
  }
}

// ---------------------------------------------------------------------------
extern "C" void kernel_launch(void* const* d_in, const int* in_sizes, int n_in,
                              void* d_out, int out_size, void* d_ws, size_t ws_size,
                              hipStream_t stream) {
  const float* x     = (const float*)d_in[0];  // [8,4096,64]
  const float* pos   = (const float*)d_in[1];  // [8,4096,3]
  const float* W     = (const float*)d_in[2];  // [128,64]
  const float* bias  = (const float*)d_in[3];  // [128]
  const float* gamma = (const float*)d_in[4];  // [128]
  const float* beta  = (const float*)d_in[5];  // [128]

  float* out_knn = (float*)d_out;                       // [8,1024,128]
  float* out_pos = out_knn + (size_t)NBATCH * NS * NO;  // [8,1024,3]

  char* ws = (char*)d_ws;
  int* fps_idx   = (int*)(ws);                 // 8*1024 ints    (32KB)
  float* partial = (float*)(ws + (32 << 10));  // 512*256 floats (512KB)
  float* ab      = (float*)(ws + (544 << 10)); // 256 floats

  fps_stats_kernel<<<8 + 256, 256, 0, stream>>>(pos, x, W, bias, fps_idx,
                                                out_pos, partial);
  stats_reduce_kernel<<<1, 256, 0, stream>>>(partial, gamma, beta, ab);
  knn_gather_kernel<<<dim3(32, NBATCH), 256, 0, stream>>>(pos, fps_idx, x, W,
                                                          bias, ab, out_knn);
}

// Round 8
// 1089.658 us; speedup vs baseline: 1.0601x; 1.0447x over previous
//
#include <hip/hip_runtime.h>
#include <stdint.h>

typedef unsigned long long ull;
typedef float f32x2 __attribute__((ext_vector_type(2)));

#define NBATCH 8
#define NPTS   4096
#define NS     1024
#define NK     16
#define NF     64
#define NO     128

#define FT  256  // fps threads (4 waves, 1 per SIMD)
#define PPT 16   // points per thread

static __device__ __forceinline__ ull umax64(ull a, ull b) { return a > b ? a : b; }

// ---------------------------------------------------------------------------
// Fused kernel 1.
// Blocks 0..7: FPS (one per batch, 256 thr, 16 pts/thread).
//   Hot loop is f32-only (packed sub/mul/add in numpy's ((dx²+dy²)+dz²) order,
//   contract off => bit-exact). Per-lane winner idx recovered by equality scan
//   of the 8 md pairs (max achiever unique; f32 collisions measure-zero on
//   random data). Cross-lane: DPP carry reduce of (val,idx); lane63 publishes
//   one u64 (f32bits<<32|idx — monotone). ONE barrier/step, 4-slot merge,
//   broadcast coord read.
// Blocks 8..263: per-channel partial sums of h = x W^T + b (stats).
// ---------------------------------------------------------------------------
__global__ __launch_bounds__(256) void fps_stats_kernel(
    const float* __restrict__ pos, const float* __restrict__ x,
    const float* __restrict__ W, const float* __restrict__ bias,
    int* __restrict__ fps_idx, float* __restrict__ out_pos,
    float* __restrict__ partial) {
#pragma clang fp contract(off)
  const int t = threadIdx.x;
  __shared__ float plds[NPTS * 3];  // fps: points | stats: x tile (32KB used)
  __shared__ __align__(16) ull wslot[2][4];
  __shared__ int widx_lds[NS];

  if (blockIdx.x >= 8) {
    // ------------------------- stats branch --------------------------------
    const int blk = blockIdx.x - 8;
    const int c = t & 127;
    const int h = t >> 7;
    float* xl = plds;

    const float4* Wv = (const float4*)(W + c * NF);
    float4 w[16];
#pragma unroll
    for (int q = 0; q < 16; ++q) w[q] = Wv[q];
    const float bb = bias[c];

    const float4* src = (const float4*)(x + (size_t)blk * 128 * NF);
    float4* dst = (float4*)xl;
    for (int i = t; i < 128 * NF / 4; i += 256) dst[i] = src[i];
    __syncthreads();

    float s = 0.f, s2 = 0.f;
    for (int r = h * 64; r < h * 64 + 64; ++r) {
      const float4* xr = (const float4*)(xl + r * NF);
      float hh = bb;
#pragma unroll
      for (int q = 0; q < 16; ++q) {
        const float4 xv = xr[q];
        hh = fmaf(xv.x, w[q].x, hh);
        hh = fmaf(xv.y, w[q].y, hh);
        hh = fmaf(xv.z, w[q].z, hh);
        hh = fmaf(xv.w, w[q].w, hh);
      }
      s += hh;
      s2 = fmaf(hh, hh, s2);
    }
    partial[(blk * 2 + h) * 256 + c] = s;
    partial[(blk * 2 + h) * 256 + 128 + c] = s2;
    return;
  }

  // --------------------------- fps branch ----------------------------------
  const int b = blockIdx.x;
  const float* p = pos + (size_t)b * NPTS * 3;
  {
    const float4* src = (const float4*)p;
    float4* dst = (float4*)plds;
    for (int i = t; i < NPTS * 3 / 4; i += FT) dst[i] = src[i];
  }
  if (t == 0) widx_lds[0] = 0;
  __syncthreads();

  f32x2 px2[PPT / 2], py2[PPT / 2], pz2[PPT / 2], md2[PPT / 2];
#pragma unroll
  for (int jp = 0; jp < PPT / 2; ++jp) {
    const int i0 = t + FT * (2 * jp);
    const int i1 = i0 + FT;
    px2[jp] = (f32x2){plds[3 * i0 + 0], plds[3 * i1 + 0]};
    py2[jp] = (f32x2){plds[3 * i0 + 1], plds[3 * i1 + 1]};
    pz2[jp] = (f32x2){plds[3 * i0 + 2], plds[3 * i1 + 2]};
    md2[jp] = (f32x2){1e10f, 1e10f};
  }

  float lx = plds[0], ly = plds[1], lz = plds[2];

  for (int s = 1; s < NS; ++s) {
    const f32x2 lxv = (f32x2){lx, lx};
    const f32x2 lyv = (f32x2){ly, ly};
    const f32x2 lzv = (f32x2){lz, lz};
    f32x2 acc = (f32x2){0.f, 0.f};
#pragma unroll
    for (int jp = 0; jp < PPT / 2; ++jp) {
      const f32x2 dx = px2[jp] - lxv;  // IEEE f32, numpy order
      const f32x2 dy = py2[jp] - lyv;
      const f32x2 dz = pz2[jp] - lzv;
      const f32x2 xx = dx * dx;
      const f32x2 yy = dy * dy;
      const f32x2 zz = dz * dz;
      const f32x2 sxy = xx + yy;
      const f32x2 d = sxy + zz;        // ((dx²+dy²)+dz²)
      md2[jp] = __builtin_elementwise_min(md2[jp], d);
      acc = __builtin_elementwise_max(acc, md2[jp]);
    }
    float best = fmaxf(acc.x, acc.y);
    // per-lane idx of the argmax-of-min (bit-equality; unique max)
    int lidx = 0;
#pragma unroll
    for (int jp = 0; jp < PPT / 2; ++jp) {
      if (md2[jp].x == best) lidx = t + FT * (2 * jp);
      if (md2[jp].y == best) lidx = t + FT * (2 * jp) + FT;
    }
    // DPP carry reduce (best, lidx) across the wave -> lane 63
#define CARRY_STEP(ctrl)                                                     \
    {                                                                        \
      const float bo = __int_as_float(__builtin_amdgcn_update_dpp(           \
          0, __float_as_int(best), ctrl, 0xf, 0xf, true));                   \
      const int io =                                                         \
          __builtin_amdgcn_update_dpp(0, lidx, ctrl, 0xf, 0xf, true);        \
      if (bo > best) { /* bound_ctrl fills 0.0 — never beats best>0 */       \
        best = bo;                                                           \
        lidx = io;                                                           \
      }                                                                      \
    }
    CARRY_STEP(0x111)  // row_shr:1
    CARRY_STEP(0x112)  // row_shr:2
    CARRY_STEP(0x114)  // row_shr:4
    CARRY_STEP(0x118)  // row_shr:8
    CARRY_STEP(0x142)  // row_bcast15
    CARRY_STEP(0x143)  // row_bcast31 -> lane 63 = wave winner
#undef CARRY_STEP
    if ((t & 63) == 63)
      wslot[s & 1][t >> 6] = ((ull)__float_as_uint(best) << 32) | (unsigned)lidx;
    __syncthreads();
    const ull* wk = wslot[s & 1];
    const ull kk =
        umax64(umax64(wk[0], wk[1]), umax64(wk[2], wk[3]));  // monotone f32 bits
    const int widx = (int)(kk & 0xFFFFFFFFu);
    lx = plds[3 * widx + 0];
    ly = plds[3 * widx + 1];
    lz = plds[3 * widx + 2];
    if (t == 0) widx_lds[s] = widx;
    // wslot double-buffered: next write to this slot (s+2) is after barrier s+1.
  }

  __syncthreads();
  for (int i = t; i < NS; i += FT) {
    const int wi = widx_lds[i];
    fps_idx[b * NS + i] = wi;
    out_pos[((size_t)b * NS + i) * 3 + 0] = plds[3 * wi + 0];
    out_pos[((size_t)b * NS + i) * 3 + 1] = plds[3 * wi + 1];
    out_pos[((size_t)b * NS + i) * 3 + 2] = plds[3 * wi + 2];
  }
}

// ---------------------------------------------------------------------------
// Stats reduce: 512 partial rows -> per-channel scale/shift.
// 1024 threads: thread (c, q) sums 64 rows; 8-way MLP + LDS tree.
// ---------------------------------------------------------------------------
__global__ __launch_bounds__(1024) void stats_reduce_kernel(
    const float* __restrict__ partial, const float* __restrict__ gamma,
    const float* __restrict__ beta, float* __restrict__ ab) {
  const int t = threadIdx.x;
  const int c = t & 127;
  const int q = t >> 7;
  __shared__ double sred[1024], s2red[1024];
  double s = 0.0, s2 = 0.0;
#pragma unroll 4
  for (int r = q * 64; r < q * 64 + 64; ++r) {
    s += (double)partial[r * 256 + c];
    s2 += (double)partial[r * 256 + 128 + c];
  }
  sred[t] = s;
  s2red[t] = s2;
  __syncthreads();
  if (t < 128) {
    s = 0.0;
    s2 = 0.0;
#pragma unroll
    for (int qq = 0; qq < 8; ++qq) {
      s += sred[qq * 128 + t];
      s2 += s2red[qq * 128 + t];
    }
    const double n = 32768.0;
    const double mean = s / n;
    const double var = s2 / n - mean * mean;
    const float inv = (float)(1.0 / sqrt(var + 1e-5));
    const float scale = gamma[t] * inv;
    const float shift = beta[t] - (float)mean * scale;
    ab[t] = scale;
    ab[128 + t] = shift;
  }
}

// ---------------------------------------------------------------------------
// Fused kernel 2: block (x,b) computes KNN for its 32 samples, then
// gathers/computes/maxes those same samples in 4 passes of 8.
// ---------------------------------------------------------------------------
__global__ __launch_bounds__(256) void knn_gather_kernel(
    const float* __restrict__ pos, const int* __restrict__ fps_idx,
    const float* __restrict__ x, const float* __restrict__ W,
    const float* __restrict__ bias, const float* __restrict__ ab,
    float* __restrict__ out) {
  __shared__ ull sbuf[NPTS * 3 / 2];  // 48KB: pos floats -> keys -> x tile
  __shared__ int il2[32 * NK];        // 2KB: knn indices, block-local samples
  float* plds = (float*)sbuf;
  const int b = blockIdx.y;
  const int t = threadIdx.x;

  const float* p = pos + (size_t)b * NPTS * 3;
  for (int i = t; i < NPTS * 3; i += 256) plds[i] = p[i];
  __syncthreads();

  {
    const int samp = blockIdx.x * 32 + (t >> 3);
    const int chunk = t & 7;
    const int sidx = fps_idx[b * NS + samp];
    const float sx = plds[sidx * 3 + 0];
    const float sy = plds[sidx * 3 + 1];
    const float sz = plds[sidx * 3 + 2];

    ull keys[16];
#pragma unroll
    for (int k = 0; k < 16; ++k) keys[k] = 0xFFFFFFFF00000000ull | (unsigned)k;
    ull worst = 0xFFFFFFFF0000000Full;

    for (int j = 0; j < 512; ++j) {
      const int i = j * 8 + chunk;
      const float dx = plds[i * 3 + 0] - sx;
      const float dy = plds[i * 3 + 1] - sy;
      const float dz = plds[i * 3 + 2] - sz;
      const float d = dx * dx + dy * dy + dz * dz;
      const ull key = ((ull)__float_as_uint(d) << 32) | (unsigned)i;
      if (key < worst) {
#pragma unroll
        for (int k = 0; k < 16; ++k) keys[k] = (keys[k] == worst) ? key : keys[k];
        ull w = keys[0];
#pragma unroll
        for (int k = 1; k < 16; ++k) w = umax64(w, keys[k]);
        worst = w;
      }
    }
    __syncthreads();  // done reading plds as floats
#pragma unroll
    for (int k = 0; k < 16; ++k) sbuf[t * 16 + k] = keys[k];
    __syncthreads();

    if (t < 32) {
      ull best[16];
#pragma unroll
      for (int k = 0; k < 16; ++k)
        best[k] = 0xFFFFFFFF00000000ull | (unsigned)(64 + k);
      ull w = 0xFFFFFFFF00000000ull | (unsigned)(64 + 15);
      for (int c = 0; c < 8; ++c) {
#pragma unroll
        for (int k = 0; k < 16; ++k) {
          const ull key = sbuf[(t * 8 + c) * 16 + k];
          if (key < w) {
#pragma unroll
            for (int q = 0; q < 16; ++q) best[q] = (best[q] == w) ? key : best[q];
            ull nw = best[0];
#pragma unroll
            for (int q = 1; q < 16; ++q) nw = umax64(nw, best[q]);
            w = nw;
          }
        }
      }
#pragma unroll
      for (int k = 0; k < 16; ++k)
        il2[t * NK + k] = (int)(best[k] & 0xFFFFFFFFu);
    }
  }

  // ----------------------------- gather phase ------------------------------
  const int c2 = t & 63;
  const int g = t >> 6;
  float4 w0[16], w1[16];
  {
    const float4* Wv0 = (const float4*)(W + c2 * NF);
    const float4* Wv1 = (const float4*)(W + (c2 + 64) * NF);
#pragma unroll
    for (int q = 0; q < 16; ++q) {
      w0[q] = Wv0[q];
      w1[q] = Wv1[q];
    }
  }
  const float bb0 = bias[c2], bb1 = bias[c2 + 64];
  const float scale0 = ab[c2], scale1 = ab[c2 + 64];
  const float shift0 = ab[128 + c2], shift1 = ab[128 + c2 + 64];

  float* xl = (float*)sbuf;  // keys region dead after il2 is written
  const float* xb = x + (size_t)b * NPTS * NF;

  for (int pass = 0; pass < 4; ++pass) {
    __syncthreads();  // il2 ready (pass 0) / previous compute done (pass>0)
    {
      const int r = t & 127;
      const int q0 = (t >> 7) * 8;
      const int idx = il2[(pass * 8 + (r >> 4)) * NK + (r & 15)];
      const float4* srow = (const float4*)(xb + (size_t)idx * NF) + q0;
      float4* drow = (float4*)(xl + r * NF) + q0;
#pragma unroll
      for (int q = 0; q < 8; ++q) drow[q] = srow[q];
    }
    __syncthreads();

#pragma unroll
    for (int sg = 0; sg < 2; ++sg) {
      const int ss = 2 * g + sg;
      float m0 = 0.0f, m1 = 0.0f;  // relu >= 0
#pragma unroll
      for (int k = 0; k < NK; ++k) {
        const float4* xr = (const float4*)(xl + (ss * 16 + k) * NF);
        float h0 = bb0, h1 = bb1;
#pragma unroll
        for (int q = 0; q < 16; ++q) {
          const float4 xv = xr[q];
          h0 = fmaf(xv.x, w0[q].x, h0);
          h0 = fmaf(xv.y, w0[q].y, h0);
          h0 = fmaf(xv.z, w0[q].z, h0);
          h0 = fmaf(xv.w, w0[q].w, h0);
          h1 = fmaf(xv.x, w1[q].x, h1);
          h1 = fmaf(xv.y, w1[q].y, h1);
          h1 = fmaf(xv.z, w1[q].z, h1);
          h1 = fmaf(xv.w, w1[q].w, h1);
        }
        h0 = fmaf(h0, scale0, shift0);
        h1 = fmaf(h1, scale1, shift1);
        h0 = h0 > 0.f ? h0 : 0.f;
        h1 = h1 > 0.f ? h1 : 0.f;
        m0 = m0 > h0 ? m0 : h0;
        m1 = m1 > h1 ? m1 : h1;
      }
      float* o = out + ((size_t)b * NS + blockIdx.x * 32 + pass * 8 + ss) * NO;
      o[c2] = m0;
      o[c2 + 64] = m1;
    }
  }
}

// ---------------------------------------------------------------------------
extern "C" void kernel_launch(void* const* d_in, const int* in_sizes, int n_in,
                              void* d_out, int out_size, void* d_ws, size_t ws_size,
                              hipStream_t stream) {
  const float* x     = (const float*)d_in[0];  // [8,4096,64]
  const float* pos   = (const float*)d_in[1];  // [8,4096,3]
  const float* W     = (const float*)d_in[2];  // [128,64]
  const float* bias  = (const float*)d_in[3];  // [128]
  const float* gamma = (const float*)d_in[4];  // [128]
  const float* beta  = (const float*)d_in[5];  // [128]

  float* out_knn = (float*)d_out;                       // [8,1024,128]
  float* out_pos = out_knn + (size_t)NBATCH * NS * NO;  // [8,1024,3]

  char* ws = (char*)d_ws;
  int* fps_idx   = (int*)(ws);                 // 8*1024 ints    (32KB)
  float* partial = (float*)(ws + (32 << 10));  // 512*256 floats (512KB)
  float* ab      = (float*)(ws + (544 << 10)); // 256 floats

  fps_stats_kernel<<<8 + 256, 256, 0, stream>>>(pos, x, W, bias, fps_idx,
                                                out_pos, partial);
  stats_reduce_kernel<<<1, 1024, 0, stream>>>(partial, gamma, beta, ab);
  knn_gather_kernel<<<dim3(32, NBATCH), 256, 0, stream>>>(pos, fps_idx, x, W,
                                                          bias, ab, out_knn);
}